// Round 1
// baseline (277.681 us; speedup 1.0000x reference)
//
#include <hip/hip_runtime.h>

typedef unsigned short u16;
typedef unsigned int   u32;
typedef __attribute__((ext_vector_type(8))) short bf16x8;
typedef __attribute__((ext_vector_type(4))) float f32x4;
typedef __attribute__((ext_vector_type(4))) u32   u32x4;

#define BB   2
#define NCH  32      // CI == CO == 32
#define DD   64
#define PD   66      // padded spatial dim (zero halo)
#define NTAP 27
#define NLOC 48      // 3 kernels x 16-channel o-group
#define WPAD 40      // 32 ci + 8 pad -> 80B rows, 2-way LDS conflict (free)

__device__ __forceinline__ u16 f2bf(float f) {
  u32 u = __float_as_uint(f);
  u = (u + 0x7fffu + ((u >> 16) & 1u)) >> 16;   // RNE
  return (u16)u;
}

// ---------------- Kernel 1: xl = log(x), channels-last bf16, zero halo -----
__global__ void build_xl_kernel(const float* __restrict__ x, u16* __restrict__ xl) {
  int tid = blockIdx.x * blockDim.x + threadIdx.x;
  const int npad = BB * PD * PD * PD;
  if (tid >= npad) return;
  int xp = tid % PD;
  int t  = tid / PD;
  int yp = t % PD;  t /= PD;
  int zp = t % PD;
  int b  = t / PD;

  u32 pk[NCH / 2];
  bool border = (xp == 0) | (xp == PD - 1) | (yp == 0) | (yp == PD - 1) |
                (zp == 0) | (zp == PD - 1);
  if (border) {
#pragma unroll
    for (int i = 0; i < NCH / 2; i++) pk[i] = 0u;
  } else {
    const float* xb = x + (size_t)b * NCH * DD * DD * DD
                        + ((size_t)(zp - 1) * DD + (yp - 1)) * DD + (xp - 1);
#pragma unroll
    for (int i = 0; i < NCH / 2; i++) {
      float v0 = xb[(size_t)(2 * i) * (DD * DD * DD)];
      float v1 = xb[(size_t)(2 * i + 1) * (DD * DD * DD)];
      u16 b0 = f2bf(__logf(v0));
      u16 b1 = f2bf(__logf(v1));
      pk[i] = (u32)b0 | ((u32)b1 << 16);
    }
  }
  u32x4* dst = (u32x4*)(xl + (size_t)tid * NCH);
#pragma unroll
  for (int i = 0; i < 4; i++) {
    u32x4 v;
    v[0] = pk[4 * i]; v[1] = pk[4 * i + 1]; v[2] = pk[4 * i + 2]; v[3] = pk[4 * i + 3];
    dst[i] = v;
  }
}

// ---------------- Kernel 2: 27-tap implicit GEMM + fused Volterra epilogue --
// block: 512 thr (8 waves). wave = 2 x-rows (128 voxels) x 48 ch (o-group's w1/w2/w3).
// grid: b(2) * z(64) * ytile(4) * ogroup(2) = 1024 blocks.

#define PREFETCH(TN, AB)                                                      \
  {                                                                           \
    int kd_ = (TN) / 9, r_ = (TN) - kd_ * 9;                                  \
    int kh_ = r_ / 3, kw_ = r_ - kh_ * 3;                                     \
    const u16* p0_ = xlb + ((kd_ * PD + kh_) * PD + kw_) * NCH;               \
    _Pragma("unroll")                                                         \
    for (int mf = 0; mf < 4; mf++)                                            \
      AB[mf] = *(const bf16x8*)(p0_ + mf * 16 * NCH);                         \
    const u16* p1_ = p0_ + PD * NCH;                                          \
    _Pragma("unroll")                                                         \
    for (int mf = 0; mf < 4; mf++)                                            \
      AB[4 + mf] = *(const bf16x8*)(p1_ + mf * 16 * NCH);                     \
  }

#define COMPUTE(TAP, AB)                                                      \
  {                                                                           \
    bf16x8 bw_[3];                                                            \
    _Pragma("unroll")                                                         \
    for (int nf = 0; nf < 3; nf++)                                            \
      bw_[nf] = *(const bf16x8*)(&lds_w[((TAP) * NLOC + nf * 16 + l15) * WPAD + l4 * 8]); \
    _Pragma("unroll")                                                         \
    for (int mf = 0; mf < 8; mf++) {                                          \
      _Pragma("unroll")                                                       \
      for (int nf = 0; nf < 3; nf++)                                          \
        acc[mf][nf] = __builtin_amdgcn_mfma_f32_16x16x32_bf16(                \
            AB[mf], bw_[nf], acc[mf][nf], 0, 0, 0);                           \
    }                                                                         \
  }

__global__ __launch_bounds__(512, 2) void conv_volterra_kernel(
    const u16* __restrict__ xl, const float* __restrict__ x,
    const float* __restrict__ w1, const float* __restrict__ w2,
    const float* __restrict__ w3, float* __restrict__ out) {
  __shared__ u16 lds_w[NTAP * NLOC * WPAD];   // 103,680 B

  const int bi = blockIdx.x;
  const int og = bi & 1;
  int t = bi >> 1;
  const int ytile = t & 3;  t >>= 2;
  const int z = t & 63;
  const int b = t >> 6;
  const int o0 = og * 16;
  const int tid = threadIdx.x;

  // ---- stage weights: lds_w[tap][c*16 + (o-o0)][ci], bf16 ----
  for (int i = tid; i < NTAP * NLOC * NCH; i += 512) {
    int ci = i & (NCH - 1);
    int q = i >> 5;
    int n = q % NLOC;
    int tap = q / NLOC;
    int c = n >> 4;
    int o = o0 + (n & 15);
    const float* ws = (c == 0) ? w1 : (c == 1) ? w2 : w3;
    float v = ws[(size_t)o * (NTAP * NCH) + tap * NCH + ci];
    lds_w[(tap * NLOC + n) * WPAD + ci] = f2bf(v);
  }
  __syncthreads();

  const int wv = tid >> 6;
  const int lane = tid & 63;
  const int l15 = lane & 15;
  const int l4 = lane >> 4;
  const int y0 = ytile * 16 + wv * 2;

  f32x4 acc[8][3];
#pragma unroll
  for (int mf = 0; mf < 8; mf++)
#pragma unroll
    for (int nf = 0; nf < 3; nf++)
      acc[mf][nf] = (f32x4){0.f, 0.f, 0.f, 0.f};

  // A fragment: row = lane&15 -> x-voxel, k = 8*(lane>>4)+j -> ci (channels-last)
  const int laneoff = l15 * NCH + l4 * 8;
  const u16* xlb = xl + (size_t)b * PD * PD * PD * NCH
                 + ((size_t)z * PD + y0) * PD * NCH + laneoff;

  bf16x8 a0[8], a1[8];
  PREFETCH(0, a0)
#pragma unroll 1
  for (int tp = 0; tp < NTAP; tp += 2) {
    if (tp + 1 < NTAP) PREFETCH(tp + 1, a1)
    COMPUTE(tp, a0)
    if (tp + 2 < NTAP) PREFETCH(tp + 2, a0)
    if (tp + 1 < NTAP) COMPUTE(tp + 1, a1)
  }

  // ---- fused epilogue: out = x * exp(l1 + l2*l3), lane-local channels ----
  const int o = o0 + l15;
  const size_t base_bo = (size_t)(b * NCH + o) * (DD * DD * DD) + (size_t)z * DD * DD;
#pragma unroll
  for (int mf = 0; mf < 8; mf++) {
    int yrow = y0 + (mf >> 2);
    int xc = (mf & 3) * 16 + l4 * 4;
    size_t idx = base_bo + (size_t)yrow * DD + xc;
    f32x4 xv = *(const f32x4*)(x + idx);
    f32x4 r;
#pragma unroll
    for (int j = 0; j < 4; j++)
      r[j] = xv[j] * __expf(acc[mf][0][j] + acc[mf][1][j] * acc[mf][2][j]);
    *(f32x4*)(out + idx) = r;
  }
}

extern "C" void kernel_launch(void* const* d_in, const int* in_sizes, int n_in,
                              void* d_out, int out_size, void* d_ws, size_t ws_size,
                              hipStream_t stream) {
  const float* x  = (const float*)d_in[0];
  const float* w1 = (const float*)d_in[1];
  const float* w2 = (const float*)d_in[2];
  const float* w3 = (const float*)d_in[3];
  float* out = (float*)d_out;
  u16* xl = (u16*)d_ws;   // 2*66^3*32 bf16 = 36.8 MB

  const int npad = BB * PD * PD * PD;
  build_xl_kernel<<<(npad + 255) / 256, 256, 0, stream>>>(x, xl);
  conv_volterra_kernel<<<1024, 512, 0, stream>>>(xl, x, w1, w2, w3, out);
}